// Round 2
// baseline (74.678 us; speedup 1.0000x reference)
//
#include <hip/hip_runtime.h>

// CharacterCNN — f32 inputs/outputs (reference dtypes), int32 ids.
// ids[65536,20], E[2,16] f32, W1[32,16,1], b1[32], W2[64,16,2], b2[64],
// W3[128,16,3], b3[128], Ht_W[224,224], Ht_b, Hg_W[224,224], Hg_b,
// P_W[64,224], P_b[64]. out f32 [65536,64].
//
// Kernel A: conv pattern LUTs in f32 (3 char-states: 0=pad,1=char0,2=char1).
// Kernel B: split Ht_W/Hg_W/P_W into hi+lo bf16 (w = hi + lo) for exact-ish
//           MFMA (weight rounding error ~2^-17).
// Kernel C: per 64-token block: masks -> LUT-max conv (cnn bf16 in LDS) ->
//           MFMA highway (hi+lo) -> MFMA projection -> direct f32 store.

typedef __attribute__((ext_vector_type(8))) __bf16 bf16x8;
typedef __attribute__((ext_vector_type(4))) float  f32x4;

#define U1OFF 0
#define U1STR 36
#define U2OFF 108
#define U2STR 68
#define U3OFF 720
#define U3STR 132
#define LUTSZ 4284              // floats
#define WS_BF_OFF 17152         // bytes, 16-aligned, past lut

// bf16 element offsets inside ws_bf
#define OThi 0
#define OTlo 50176
#define OGhi 100352
#define OGlo 150528
#define OPhi 200704
#define OPlo 215040
#define NSPLIT 114688           // 50176*2 + 14336

__device__ __forceinline__ f32x4 fmax4(f32x4 a, f32x4 b) {
  f32x4 r;
  r[0] = fmaxf(a[0], b[0]);
  r[1] = fmaxf(a[1], b[1]);
  r[2] = fmaxf(a[2], b[2]);
  r[3] = fmaxf(a[3], b[3]);
  return r;
}

// ---------------- Kernel A: LUT precompute (f32 exact) ----------------
__global__ __launch_bounds__(256) void lut_kernel(
    const float* __restrict__ E,
    const float* __restrict__ W1, const float* __restrict__ b1,
    const float* __restrict__ W2, const float* __restrict__ b2,
    const float* __restrict__ W3, const float* __restrict__ b3,
    float* __restrict__ lut)
{
  __shared__ float X[3][16];
  const int tid = threadIdx.x;
  if (tid < 48) {
    int s = tid >> 4, i = tid & 15;
    X[s][i] = (s == 0) ? 0.f : E[(s - 1) * 16 + i];
  }
  __syncthreads();
  const int gid = blockIdx.x * 256 + tid;
  const int gsz = gridDim.x * 256;

  for (int idx = gid; idx < 96; idx += gsz) {          // u1: 3 x 32
    int s = idx >> 5, c = idx & 31;
    float acc = b1[c];
    #pragma unroll
    for (int i = 0; i < 16; i++) acc += W1[c * 16 + i] * X[s][i];
    lut[U1OFF + s * U1STR + c] = acc;
  }
  for (int idx = gid; idx < 576; idx += gsz) {         // u2: 9 x 64
    int p = idx >> 6, c = idx & 63;
    int sa = p / 3, sb = p % 3;
    float acc = b2[c];
    #pragma unroll
    for (int i = 0; i < 16; i++)
      acc += W2[c * 32 + i * 2 + 0] * X[sa][i]
           + W2[c * 32 + i * 2 + 1] * X[sb][i];
    lut[U2OFF + p * U2STR + c] = acc;
  }
  for (int idx = gid; idx < 3456; idx += gsz) {        // u3: 27 x 128
    int p = idx >> 7, c = idx & 127;
    int sa = p / 9, sb = (p / 3) % 3, sc = p % 3;
    float acc = b3[c];
    #pragma unroll
    for (int i = 0; i < 16; i++)
      acc += W3[c * 48 + i * 3 + 0] * X[sa][i]
           + W3[c * 48 + i * 3 + 1] * X[sb][i]
           + W3[c * 48 + i * 3 + 2] * X[sc][i];
    lut[U3OFF + p * U3STR + c] = acc;
  }
}

// ---------------- Kernel B: weight split to hi+lo bf16 ----------------
__global__ __launch_bounds__(256) void wsplit_kernel(
    const float* __restrict__ HtW, const float* __restrict__ HgW,
    const float* __restrict__ PW, __bf16* __restrict__ wsb)
{
  int idx = blockIdx.x * 256 + threadIdx.x;
  if (idx >= NSPLIT) return;
  float w;
  int hi_off, el;
  if (idx < 50176)        { w = HtW[idx];          hi_off = OThi; el = idx; }
  else if (idx < 100352)  { w = HgW[idx - 50176];  hi_off = OGhi; el = idx - 50176; }
  else                    { w = PW[idx - 100352];  hi_off = OPhi; el = idx - 100352; }
  __bf16 hi = (__bf16)w;
  __bf16 lo = (__bf16)(w - (float)hi);
  wsb[hi_off + el] = hi;
  wsb[hi_off + 50176 * ((hi_off == OPhi) ? 0 : 1) + ((hi_off == OPhi) ? 14336 : 0) + el] = lo;
}

// ---------------- Kernel C: main ----------------
__device__ __forceinline__ void conv_max8(const float* __restrict__ lut,
                                          int base, int stride, unsigned m,
                                          __bf16* dst)
{
  f32x4 a0 = {0.f, 0.f, 0.f, 0.f}, a1 = {0.f, 0.f, 0.f, 0.f};
  while (m) {
    int b = (int)__builtin_ctz(m);
    m &= m - 1u;
    const f32x4* p = (const f32x4*)(lut + base + b * stride);
    a0 = fmax4(a0, p[0]);
    a1 = fmax4(a1, p[1]);
  }
  bf16x8 v;
  v[0] = (__bf16)a0[0]; v[1] = (__bf16)a0[1]; v[2] = (__bf16)a0[2]; v[3] = (__bf16)a0[3];
  v[4] = (__bf16)a1[0]; v[5] = (__bf16)a1[1]; v[6] = (__bf16)a1[2]; v[7] = (__bf16)a1[3];
  *(bf16x8*)dst = v;
}

__global__ __launch_bounds__(256, 2) void cnn_kernel(
    const int*   __restrict__ ids, const float* __restrict__ lut_g,
    const __bf16* __restrict__ wsb,
    const float* __restrict__ Htb, const float* __restrict__ Hgb,
    const float* __restrict__ Pb,
    float* __restrict__ out, int n_tok)
{
  __shared__ __attribute__((aligned(16))) float lut[LUTSZ];
  __shared__ float biasT[224], biasG[224], biasP[64];
  __shared__ unsigned masks[64][4];
  __shared__ __attribute__((aligned(16))) __bf16 cnn[64][232];   // 224 + pad

  const int tid = threadIdx.x;
  const int tok0 = blockIdx.x * 64;

  for (int i = tid; i < LUTSZ; i += 256) lut[i] = lut_g[i];
  for (int i = tid; i < 224; i += 256) {
    biasT[i] = Htb[i];
    biasG[i] = Hgb[i];
  }
  if (tid < 64) biasP[tid] = Pb[tid];

  if (tid < 64) {
    unsigned m1 = 0, m2 = 0, m3 = 0;
    if (tok0 + tid < n_tok) {
      const int4* idp4 = (const int4*)(ids + (size_t)(tok0 + tid) * 20);
      int st[22];
      st[0] = 0; st[21] = 0;
      #pragma unroll
      for (int q = 0; q < 5; q++) {
        int4 v = idp4[q];
        st[q * 4 + 1] = v.x + 1; st[q * 4 + 2] = v.y + 1;
        st[q * 4 + 3] = v.z + 1; st[q * 4 + 4] = v.w + 1;
      }
      #pragma unroll
      for (int l = 0; l < 20; l++) m1 |= 1u << st[l + 1];
      #pragma unroll
      for (int l = 0; l < 21; l++) m2 |= 1u << (st[l] * 3 + st[l + 1]);
      #pragma unroll
      for (int l = 0; l < 20; l++) m3 |= 1u << (st[l] * 9 + st[l + 1] * 3 + st[l + 2]);
    }
    masks[tid][0] = m1; masks[tid][1] = m2; masks[tid][2] = m3;
  }
  __syncthreads();

  // ---- phase 1: conv LUT-max -> cnn[64][224] (bf16) ----
  {
    int tok = tid >> 2, g = tid & 3;                       // conv1: 32ch
    conv_max8(lut, U1OFF + g * 8, U1STR, masks[tok][0], &cnn[tok][g * 8]);
  }
  #pragma unroll
  for (int it = 0; it < 2; it++) {                         // conv2: 64ch
    int item = tid + it * 256;
    int tok = item >> 3, g = item & 7;
    conv_max8(lut, U2OFF + g * 8, U2STR, masks[tok][1], &cnn[tok][32 + g * 8]);
  }
  #pragma unroll
  for (int it = 0; it < 4; it++) {                         // conv3: 128ch
    int item = tid + it * 256;
    int tok = item >> 4, g = item & 15;
    conv_max8(lut, U3OFF + g * 8, U3STR, masks[tok][2], &cnn[tok][96 + g * 8]);
  }
  __syncthreads();

  // ---- phase 2: highway via MFMA, waves split the 14 N-frags (4/4/3/3) ----
  const int wave = tid >> 6, lane = tid & 63;
  const int lrow = lane & 15;            // A row-in-frag / B col-in-frag
  const int kg8 = (lane >> 4) * 8;       // k offset within 32-wide K frag
  const int rr0 = (lane >> 4) * 4;       // C/D row base

  bf16x8 af[4][7];
  #pragma unroll
  for (int mf = 0; mf < 4; mf++)
    #pragma unroll
    for (int kf = 0; kf < 7; kf++)
      af[mf][kf] = *(const bf16x8*)&cnn[mf * 16 + lrow][kf * 32 + kg8];
  __syncthreads();   // all waves captured cnn before in-place hw overwrite

  const int nf_begin = (wave < 2) ? wave * 4 : 8 + (wave - 2) * 3;
  const int nf_cnt   = (wave < 2) ? 4 : 3;
  for (int ni = 0; ni < nf_cnt; ni++) {
    const int nf = nf_begin + ni;
    const int col = nf * 16 + lrow;
    const __bf16* pThi = wsb + OThi + (size_t)col * 224 + kg8;
    const __bf16* pTlo = wsb + OTlo + (size_t)col * 224 + kg8;
    const __bf16* pGhi = wsb + OGhi + (size_t)col * 224 + kg8;
    const __bf16* pGlo = wsb + OGlo + (size_t)col * 224 + kg8;
    const float bt = biasT[col], bg = biasG[col];
    f32x4 aT[4], aG[4];
    #pragma unroll
    for (int mf = 0; mf < 4; mf++) {
      aT[mf] = (f32x4){bt, bt, bt, bt};
      aG[mf] = (f32x4){bg, bg, bg, bg};
    }
    #pragma unroll
    for (int kf = 0; kf < 7; kf++) {
      bf16x8 wThi = *(const bf16x8*)(pThi + kf * 32);
      bf16x8 wTlo = *(const bf16x8*)(pTlo + kf * 32);
      bf16x8 wGhi = *(const bf16x8*)(pGhi + kf * 32);
      bf16x8 wGlo = *(const bf16x8*)(pGlo + kf * 32);
      #pragma unroll
      for (int mf = 0; mf < 4; mf++) {
        aT[mf] = __builtin_amdgcn_mfma_f32_16x16x32_bf16(af[mf][kf], wThi, aT[mf], 0, 0, 0);
        aT[mf] = __builtin_amdgcn_mfma_f32_16x16x32_bf16(af[mf][kf], wTlo, aT[mf], 0, 0, 0);
        aG[mf] = __builtin_amdgcn_mfma_f32_16x16x32_bf16(af[mf][kf], wGhi, aG[mf], 0, 0, 0);
        aG[mf] = __builtin_amdgcn_mfma_f32_16x16x32_bf16(af[mf][kf], wGlo, aG[mf], 0, 0, 0);
      }
    }
    #pragma unroll
    for (int mf = 0; mf < 4; mf++)
      #pragma unroll
      for (int r = 0; r < 4; r++) {
        int row = mf * 16 + rr0 + r;
        float t  = fmaxf(aT[mf][r], 0.f);
        float gg = 1.f / (1.f + __expf(-aG[mf][r]));
        float cv = (float)cnn[row][col];
        cnn[row][col] = (__bf16)(cv + gg * (t - cv));   // hw, in place
      }
  }
  __syncthreads();

  // ---- phase 3: projection (each wave owns 16 of 64 out channels) ----
  #pragma unroll
  for (int mf = 0; mf < 4; mf++)
    #pragma unroll
    for (int kf = 0; kf < 7; kf++)
      af[mf][kf] = *(const bf16x8*)&cnn[mf * 16 + lrow][kf * 32 + kg8];
  {
    const int col = wave * 16 + lrow;
    const __bf16* pPhi = wsb + OPhi + (size_t)col * 224 + kg8;
    const __bf16* pPlo = wsb + OPlo + (size_t)col * 224 + kg8;
    const float bp = biasP[col];
    f32x4 ac[4];
    #pragma unroll
    for (int mf = 0; mf < 4; mf++) ac[mf] = (f32x4){bp, bp, bp, bp};
    #pragma unroll
    for (int kf = 0; kf < 7; kf++) {
      bf16x8 wPhi = *(const bf16x8*)(pPhi + kf * 32);
      bf16x8 wPlo = *(const bf16x8*)(pPlo + kf * 32);
      #pragma unroll
      for (int mf = 0; mf < 4; mf++) {
        ac[mf] = __builtin_amdgcn_mfma_f32_16x16x32_bf16(af[mf][kf], wPhi, ac[mf], 0, 0, 0);
        ac[mf] = __builtin_amdgcn_mfma_f32_16x16x32_bf16(af[mf][kf], wPlo, ac[mf], 0, 0, 0);
      }
    }
    // direct f32 store from C-layout: 4 x 64B contiguous segments per step
    #pragma unroll
    for (int mf = 0; mf < 4; mf++)
      #pragma unroll
      for (int r = 0; r < 4; r++) {
        int row = mf * 16 + rr0 + r;
        if (tok0 + row < n_tok)
          out[(size_t)(tok0 + row) * 64 + col] = ac[mf][r];
      }
  }
}

extern "C" void kernel_launch(void* const* d_in, const int* in_sizes, int n_in,
                              void* d_out, int out_size, void* d_ws, size_t ws_size,
                              hipStream_t stream) {
  const int*   ids = (const int*)d_in[0];
  const float* E   = (const float*)d_in[1];
  const float* W1  = (const float*)d_in[2];
  const float* b1  = (const float*)d_in[3];
  const float* W2  = (const float*)d_in[4];
  const float* b2  = (const float*)d_in[5];
  const float* W3  = (const float*)d_in[6];
  const float* b3  = (const float*)d_in[7];
  const float* HtW = (const float*)d_in[8];
  const float* Htb = (const float*)d_in[9];
  const float* HgW = (const float*)d_in[10];
  const float* Hgb = (const float*)d_in[11];
  const float* PW  = (const float*)d_in[12];
  const float* Pb  = (const float*)d_in[13];
  float*  out = (float*)d_out;
  float*  lut = (float*)d_ws;
  __bf16* wsb = (__bf16*)((char*)d_ws + WS_BF_OFF);

  const int n_tok = in_sizes[0] / 20;
  lut_kernel<<<16, 256, 0, stream>>>(E, W1, b1, W2, b2, W3, b3, lut);
  wsplit_kernel<<<(NSPLIT + 255) / 256, 256, 0, stream>>>(HtW, HgW, PW, wsb);
  cnn_kernel<<<(n_tok + 63) / 64, 256, 0, stream>>>(
      ids, lut, wsb, Htb, Hgb, Pb, out, n_tok);
}